// Round 1
// baseline (572.048 us; speedup 1.0000x reference)
//
#include <hip/hip_runtime.h>
#include <hip/hip_bf16.h>

typedef __attribute__((ext_vector_type(4))) float floatx4;
typedef __bf16 bf16x8 __attribute__((ext_vector_type(8)));

static __device__ __forceinline__ unsigned short f2bf(float x) {
    union { float f; unsigned int u; } v; v.f = x;
    unsigned int u = v.u;
    unsigned int r = u + 0x7FFF + ((u >> 16) & 1);   // round-to-nearest-even
    return (unsigned short)(r >> 16);
}

// Kernel 1: per-node transform. 2 nodes per block, 256 threads.
//   support[k] = sum_j in[j] * W[n][j][k]   (thread-private float4 accum, coalesced)
//   h[j]      = sum_k R[n][j][k] * support[k]  (half-wave per row, shfl reduce)
// Writes h transposed as bf16: h_t[feature j][node n]  (so K2 B-frags are k-contiguous)
__global__ __launch_bounds__(256) void node_transform(
    const float* __restrict__ input,      // [4096][128]
    const float* __restrict__ rel,        // [4096][128][128]
    const float* __restrict__ wts,        // [4096][128][128]
    unsigned int* __restrict__ h_t)       // [128][2048] uint = [128][4096] bf16
{
    __shared__ float s_in[2][128];
    __shared__ float s_part[2][4][128];
    __shared__ float s_sup[2][128];
    __shared__ float s_h[2][128];

    const int tid = threadIdx.x;
    const int b = blockIdx.x;

    // load input rows for both nodes (256 floats = 64 float4, contiguous)
    if (tid < 64) {
        float4 v = ((const float4*)input)[b * 64 + tid];
        ((float4*)&s_in[0][0])[tid] = v;
    }
    __syncthreads();

    const int node = tid >> 7;          // 0/1
    const int tl   = tid & 127;         // thread-in-node
    const int n    = b * 2 + node;

    // ---- stage 1: support = in^T * W ----
    {
        const int jg = tl >> 5;         // 0..3  (j-group of 32 rows)
        const int kq = tl & 31;         // float4 column quad
        const float4* W4 = (const float4*)(wts + (size_t)n * 16384);
        float4 acc = {0.f, 0.f, 0.f, 0.f};
        const int j0 = jg * 32;
        #pragma unroll 8
        for (int jj = 0; jj < 32; ++jj) {
            const int j = j0 + jj;
            const float x = s_in[node][j];
            const float4 w = W4[j * 32 + kq];     // coalesced: 32 lanes x 16B contig
            acc.x += x * w.x; acc.y += x * w.y;
            acc.z += x * w.z; acc.w += x * w.w;
        }
        ((float4*)&s_part[node][jg][0])[kq] = acc;
    }
    __syncthreads();
    // reduce the 4 j-group partials; tl == k
    s_sup[node][tl] = s_part[node][0][tl] + s_part[node][1][tl]
                    + s_part[node][2][tl] + s_part[node][3][tl];
    __syncthreads();

    // ---- stage 2: h = R * support ----
    {
        const int wnode = tl >> 6;      // wave within node: 0/1
        const int lane  = tl & 63;
        const int half  = lane >> 5;    // row parity within iteration
        const int l     = lane & 31;    // 32 lanes cover one 128-float row as float4
        const float4* R4 = (const float4*)(rel + (size_t)n * 16384);
        const float4 sv = ((const float4*)&s_sup[node][0])[l];  // reused all iters
        #pragma unroll 4
        for (int it = 0; it < 32; ++it) {
            const int j = wnode * 64 + it * 2 + half;
            const float4 r = R4[j * 32 + l];      // coalesced 512B per row
            float p = r.x * sv.x + r.y * sv.y + r.z * sv.z + r.w * sv.w;
            p += __shfl_xor(p, 1);
            p += __shfl_xor(p, 2);
            p += __shfl_xor(p, 4);
            p += __shfl_xor(p, 8);
            p += __shfl_xor(p, 16);               // reduce within 32-lane half
            if (l == 0) s_h[node][j] = p;
        }
    }
    __syncthreads();

    // pack both nodes' h[j] into one dword, store to transposed layout
    if (tid < 128) {
        const unsigned int lo = f2bf(s_h[0][tid]);
        const unsigned int hi = f2bf(s_h[1][tid]);
        h_t[tid * 2048 + b] = lo | (hi << 16);    // bytes j*8192 + 4*b
    }
}

// Kernel 2: out = adj @ h + bias, bf16 MFMA.
// Block: 16 rows x 128 cols, 8 waves (one 16x16 acc each), BK=128, grid 256.
__global__ __launch_bounds__(512) void agg_gemm(
    const float* __restrict__ A,              // [4096][4096] fp32 adjacency
    const unsigned short* __restrict__ ht,    // [128][4096] bf16 (h transposed)
    const float* __restrict__ bias,           // [128]
    float* __restrict__ out)                  // [4096][128] fp32
{
    // +8 bf16 pad per row -> stride 272B: uniform 8-lanes-per-bank-group b128 reads
    __shared__ __align__(16) unsigned short As[16][136];
    __shared__ __align__(16) unsigned short Bs[128][136];

    const int tid  = threadIdx.x;
    const int wave = tid >> 6;                // 0..7 -> col group
    const int lane = tid & 63;
    const int m0   = blockIdx.x * 16;

    floatx4 acc = {0.f, 0.f, 0.f, 0.f};

    const int ar = tid >> 5;                  // A stage: row 0..15
    const int ac = (tid & 31) * 4;            //          col quad
    const int bj = tid >> 2;                  // B stage: feature row 0..127
    const int bs = tid & 3;                   //          16B sub-chunk

    for (int kb = 0; kb < 4096; kb += 128) {
        __syncthreads();                      // protect LDS from previous iter reads
        // stage A tile: 16 x 128 fp32 -> bf16 (512 thr x 1 float4, coalesced)
        {
            const float4 v = *(const float4*)(A + (size_t)(m0 + ar) * 4096 + kb + ac);
            const unsigned int p0 = (unsigned int)f2bf(v.x) | ((unsigned int)f2bf(v.y) << 16);
            const unsigned int p1 = (unsigned int)f2bf(v.z) | ((unsigned int)f2bf(v.w) << 16);
            *(uint2*)&As[ar][ac] = make_uint2(p0, p1);
        }
        // stage B tile: 128 x 128 bf16 (512 thr x 4 uint4; 64B contig per 4 lanes)
        {
            const unsigned short* src = ht + (size_t)bj * 4096 + kb + bs * 8;
            #pragma unroll
            for (int i = 0; i < 4; ++i) {
                const uint4 v = *(const uint4*)(src + i * 32);
                *(uint4*)&Bs[bj][bs * 8 + i * 32] = v;
            }
        }
        __syncthreads();
        // compute: wave covers cols [wave*16, wave*16+16)
        const int mn = lane & 15;             // A row m / B col n
        const int kq = lane >> 4;             // k-quad: 8 contiguous k per lane
        const unsigned short* arow = &As[mn][kq * 8];
        const unsigned short* brow = &Bs[wave * 16 + mn][kq * 8];
        #pragma unroll
        for (int k0 = 0; k0 < 128; k0 += 32) {
            const bf16x8 af = *(const bf16x8*)(arow + k0);
            const bf16x8 bfr = *(const bf16x8*)(brow + k0);
            acc = __builtin_amdgcn_mfma_f32_16x16x32_bf16(af, bfr, acc, 0, 0, 0);
        }
    }

    // epilogue: C/D layout col=lane&15, row=(lane>>4)*4+reg
    const int col = wave * 16 + (lane & 15);
    const int r0  = (lane >> 4) * 4;
    const float bv = bias[col];
    #pragma unroll
    for (int r = 0; r < 4; ++r) {
        out[(size_t)(m0 + r0 + r) * 128 + col] = acc[r] + bv;
    }
}

extern "C" void kernel_launch(void* const* d_in, const int* in_sizes, int n_in,
                              void* d_out, int out_size, void* d_ws, size_t ws_size,
                              hipStream_t stream) {
    const float* input = (const float*)d_in[0];   // [4096][128]
    const float* adj   = (const float*)d_in[1];   // [4096][4096]
    const float* rel   = (const float*)d_in[2];   // [4096][128][128]
    const float* wts   = (const float*)d_in[3];   // [4096][128][128]
    const float* bias  = (const float*)d_in[4];   // [128]
    float* out = (float*)d_out;

    unsigned int* h_t = (unsigned int*)d_ws;      // 1 MB bf16 h, transposed [128][4096]

    node_transform<<<2048, 256, 0, stream>>>(input, rel, wts, h_t);
    agg_gemm<<<256, 512, 0, stream>>>(adj, (const unsigned short*)d_ws, bias, out);
}